// Round 8
// baseline (1145.469 us; speedup 1.0000x reference)
//
#include <hip/hip_runtime.h>

// IndRNN: two layers of (GEMM pre-projection + elementwise scan).
//   T=1024, B=64, I=512, H=2048.
// R8: revert to R6's 16x16x32 gemm8 (32x32 port had a +5e7 bank-conflict
// penalty on fragment reads — mechanism unexplained by slot model, reverted).
// One intra-phase reorder: stage* issues hoisted ABOVE each phase's ds_read
// cluster (HBM fetch starts ~60-100cy earlier; vmcnt queue order preserved).

#define T_SEQ 1024
#define NB 64
#define NI 512
#define NH 2048
#define BH (NB * NH)
#define M_ROWS (T_SEQ * NB)

typedef _Float16 f16;
typedef __attribute__((ext_vector_type(8))) _Float16 f16x8;
typedef __attribute__((ext_vector_type(4))) _Float16 f16x4;
typedef __attribute__((ext_vector_type(4))) float f32x4;

__device__ __forceinline__ void gload_lds16(const f16* g, const f16* lds) {
  __builtin_amdgcn_global_load_lds(
      (const __attribute__((address_space(1))) unsigned int*)g,
      (__attribute__((address_space(3))) unsigned int*)lds, 16, 0, 0);
}
__device__ __forceinline__ void barrier_raw() {
  __builtin_amdgcn_sched_barrier(0);
  __builtin_amdgcn_s_barrier();
  __builtin_amdgcn_sched_barrier(0);
}
// rule 18: inline-asm lgkmcnt(0) needs a following sched_barrier(0)
#define LGKM0()                                        \
  do {                                                 \
    asm volatile("s_waitcnt lgkmcnt(0)" ::: "memory"); \
    __builtin_amdgcn_sched_barrier(0);                 \
  } while (0)
#define VMCNT4() asm volatile("s_waitcnt vmcnt(4)" ::: "memory")

// ---------------- fp32 -> fp16 conversion, all 3 inputs in one launch -------
__global__ __launch_bounds__(256)
void cvt_all(const float* __restrict__ x, const float* __restrict__ w0,
             const float* __restrict__ w1, f16* __restrict__ x16,
             f16* __restrict__ w0_16, f16* __restrict__ w1_16) {
  constexpr int N0 = 33554432 / 4, N1 = 1048576 / 4, N2 = 4194304 / 4;
  int i = blockIdx.x * 256 + threadIdx.x;
  const int stride = gridDim.x * 256;
  for (; i < N0 + N1 + N2; i += stride) {
    const float* src; f16* dst; int j;
    if (i < N0)            { src = x;  dst = x16;   j = i; }
    else if (i < N0 + N1)  { src = w0; dst = w0_16; j = i - N0; }
    else                   { src = w1; dst = w1_16; j = i - N0 - N1; }
    f32x4 v = ((const f32x4*)src)[j];
    f16x4 h;
    h[0] = (f16)v[0]; h[1] = (f16)v[1]; h[2] = (f16)v[2]; h[3] = (f16)v[3];
    ((f16x4*)dst)[j] = h;
  }
}

// ------- GEMM: C[M,2048] = A[M,K] * Bt[2048,K]^T + bias, 8-phase 256^2 -------
// Wave (wr,wc): wr=wid>>2 (2 M-groups), wc=wid&3 (4 N-groups).
// m-tile mt(0..7) -> C rows (2*mt+wr)*16; A-half = mt>>2 (interleave-by-16).
// n-tile nt(0..3) -> C cols (4*nt+wc)*16; B-half = nt>>1.
// Phases per K-tile: (m0,n0)(m0,n1)(m1,n1)(m1,n0); stages: A1(t+1), B0(t+1),
// A0(t+2), B1(t+2); vmcnt(4) at phase 3 only. Queue proof: end of tile t,
// outstanding = [A0(t+1),B1(t+1)] carried + this tile's 4 stages = 12 instr;
// drain to 4 completes all of t+1, leaves [A0(t+2),B1(t+2)].
template <int K, typename OutT>
__global__ __launch_bounds__(512, 2)
void gemm8(const f16* __restrict__ A, const f16* __restrict__ Bt,
           const float* __restrict__ bias, OutT* __restrict__ C) {
  constexpr int NT = K / 64;
  __shared__ f16 sA[2][2][128 * 64];   // [buf][half][row 128][k 64]
  __shared__ f16 sB[2][2][128 * 64];

  const int tid = threadIdx.x, wid = tid >> 6, lane = tid & 63;
  int id = (int)blockIdx.x;
  id = (id & 7) * 256 + (id >> 3);          // XCD swizzle (2048 % 8 == 0)
  const int bn = id & 7, bm = id >> 3;
  const long m0 = (long)bm * 256, n0 = (long)bn * 256;

  const int wr = wid >> 2, wc = wid & 3;
  const int lrow = lane & 15, lk = (lane >> 4) * 8;

  // ds_read byte offsets: L = (tilebase) + ks*64 + T; phys = L ^ ((row&7)<<4).
  const int xorv = (lrow & 7) << 4;
  const int TxA = (((wr * 16 + lrow) * 128) + lk * 2) ^ xorv;
  const int TxB = (((wc * 16 + lrow) * 128) + lk * 2) ^ xorv;

  auto ldA = [&](int buf, int mt, int ks) -> f16x8 {
    const char* p = (const char*)&sA[buf][mt >> 2][0];
    return *(const f16x8*)(p + (mt & 3) * 4096 + (TxA ^ (ks << 6)));
  };
  auto ldB = [&](int buf, int nt, int ks) -> f16x8 {
    const char* p = (const char*)&sB[buf][nt >> 1][0];
    return *(const f16x8*)(p + (nt & 1) * 8192 + (TxB ^ (ks << 6)));
  };

  // staging: LDS dest linear (base + lane*16 by HW); source pre-swizzled.
  const int srow = wid * 8 + (lane >> 3);
  const int scol = ((lane & 7) ^ ((lane >> 3) & 7)) * 8;
  const int ldst = wid * 512;   // f16 elements; +4096 for inst 1

  auto stageA = [&](int buf, int h, int kt) {
    if (kt >= NT) kt = NT - 1;   // tail clamp: lands in a dead buffer
    const f16* g = A + (m0 + h * 128 + srow) * (long)K + kt * 64 + scol;
    gload_lds16(g,                &sA[buf][h][ldst]);
    gload_lds16(g + 64 * (long)K, &sA[buf][h][ldst + 4096]);
  };
  auto stageB = [&](int buf, int h, int kt) {
    if (kt >= NT) kt = NT - 1;
    const f16* g = Bt + (n0 + h * 128 + srow) * (long)K + kt * 64 + scol;
    gload_lds16(g,                &sB[buf][h][ldst]);
    gload_lds16(g + 64 * (long)K, &sB[buf][h][ldst + 4096]);
  };

  f32x4 acc[8][4] = {};
  f16x8 aR[4][2], bR[4][2];

#define MFMA16(MBASE, NBASE)                                                   \
  __builtin_amdgcn_s_setprio(1);                                               \
  _Pragma("unroll") for (int mi = 0; mi < 4; ++mi)                             \
      _Pragma("unroll") for (int ni = 0; ni < 2; ++ni)                         \
          _Pragma("unroll") for (int ks = 0; ks < 2; ++ks)                     \
              acc[MBASE + mi][NBASE + ni] =                                    \
                  __builtin_amdgcn_mfma_f32_16x16x32_f16(                      \
                      aR[mi][ks], bR[NBASE + ni][ks],                          \
                      acc[MBASE + mi][NBASE + ni], 0, 0, 0);                   \
  __builtin_amdgcn_s_setprio(0);

  // prologue — queue order must match steady state:
  stageA(0, 0, 0);
  stageB(0, 1, 0);
  stageA(0, 1, 0);
  stageB(0, 0, 0);
  stageA(1, 0, 1);
  stageB(1, 1, 1);
  VMCNT4();
  barrier_raw();

  for (int t = 0; t < NT; ++t) {
    const int cur = t & 1, nxt = cur ^ 1;
    // ---- phase 0: (m0,n0); stage A1(t+1) first; ds: A-half0 + B-half0 ----
    stageA(nxt, 1, t + 1);
#pragma unroll
    for (int i = 0; i < 4; ++i) { aR[i][0] = ldA(cur, i, 0); aR[i][1] = ldA(cur, i, 1); }
#pragma unroll
    for (int i = 0; i < 2; ++i) { bR[i][0] = ldB(cur, i, 0); bR[i][1] = ldB(cur, i, 1); }
    barrier_raw();
    LGKM0();
    MFMA16(0, 0);
    barrier_raw();
    // ---- phase 1: (m0,n1); stage B0(t+1) first; ds: B-half1 ----
    stageB(nxt, 0, t + 1);
#pragma unroll
    for (int i = 0; i < 2; ++i) { bR[2 + i][0] = ldB(cur, 2 + i, 0); bR[2 + i][1] = ldB(cur, 2 + i, 1); }
    barrier_raw();
    LGKM0();
    MFMA16(0, 2);
    barrier_raw();
    // ---- phase 2: (m1,n1); stage A0(t+2) first; ds: A-half1 ----
    stageA(cur, 0, t + 2);
#pragma unroll
    for (int i = 0; i < 4; ++i) { aR[i][0] = ldA(cur, 4 + i, 0); aR[i][1] = ldA(cur, 4 + i, 1); }
    barrier_raw();
    LGKM0();
    MFMA16(4, 2);
    barrier_raw();
    // ---- phase 3: (m1,n0); stage B1(t+2); no ds; counted vmcnt ----
    stageB(cur, 1, t + 2);
    barrier_raw();
    MFMA16(4, 0);
    VMCNT4();
    barrier_raw();
  }

  // ---- epilogue: D frag col=lane&15, row=(lane>>4)*4+j ----
  float bv[4];
#pragma unroll
  for (int nt = 0; nt < 4; ++nt) bv[nt] = bias[n0 + (4 * nt + wc) * 16 + lrow];
#pragma unroll
  for (int mt = 0; mt < 8; ++mt) {
    const long rbase = m0 + (2 * mt + wr) * 16 + ((lane >> 4) << 2);
#pragma unroll
    for (int j = 0; j < 4; ++j) {
      OutT* cp = C + (rbase + j) * (long)NH + n0 + wc * 16 + lrow;
#pragma unroll
      for (int nt = 0; nt < 4; ++nt)
        cp[nt * 64] = (OutT)(acc[mt][nt][j] + bv[nt]);
    }
  }
#undef MFMA16
}

// ------------- scan: h[t] = relu(pre[t] + w*h[t-1]); out[t] = h -------------
// One thread per (b,h) channel; fp32 state in regs; 16-deep software prefetch.
// No __restrict__: in==out for the in-place layer-0 use.
template <typename InT, typename OutT>
__global__ __launch_bounds__(256)
void scan_k(const InT* in, OutT* out, const float* __restrict__ w_hh) {
  const int c = blockIdx.x * 256 + threadIdx.x;   // 0..BH-1
  const float w = w_hh[c & (NH - 1)];
  const InT* pi = in + c;
  OutT* po = out + c;
  float h = 0.f, v[16], n[16];
#pragma unroll
  for (int j = 0; j < 16; ++j) v[j] = (float)pi[(long)j * BH];
  for (int t = 0; t < T_SEQ; t += 16) {
    if (t + 16 < T_SEQ) {
#pragma unroll
      for (int j = 0; j < 16; ++j) n[j] = (float)pi[(long)(t + 16 + j) * BH];
    } else {
#pragma unroll
      for (int j = 0; j < 16; ++j) n[j] = 0.f;
    }
#pragma unroll
    for (int j = 0; j < 16; ++j) {
      h = fmaxf(fmaf(w, h, v[j]), 0.f);
      po[(long)(t + j) * BH] = (OutT)h;
      v[j] = n[j];
    }
  }
}

extern "C" void kernel_launch(void* const* d_in, const int* in_sizes, int n_in,
                              void* d_out, int out_size, void* d_ws, size_t ws_size,
                              hipStream_t stream) {
  const float* x     = (const float*)d_in[0];   // [1024,64,512]
  const float* w_ih0 = (const float*)d_in[1];   // [2048,512]
  const float* w_hh0 = (const float*)d_in[2];   // [2048]
  const float* b0    = (const float*)d_in[3];   // [2048]
  const float* w_ih1 = (const float*)d_in[4];   // [2048,2048]
  const float* w_hh1 = (const float*)d_in[5];   // [2048]
  const float* b1    = (const float*)d_in[6];   // [2048]
  float* out = (float*)d_out;                   // [1024,64,2048]

  char* ws = (char*)d_ws;
  f16* x16   = (f16*)(ws);                 // 64 MiB
  f16* w0_16 = (f16*)(ws + 67108864);      //  2 MiB
  f16* w1_16 = (f16*)(ws + 69206016);      //  8 MiB
  f16* P     = (f16*)(ws + 77594624);      // 256 MiB (pre0 -> h0, in-place)
  f16* P2    = (f16*)(ws + 346030080);     // 256 MiB (pre1 fp16), if ws allows
  const bool p2_f16 = ws_size >= (size_t)346030080 + 268435456;

  cvt_all<<<2048, 256, 0, stream>>>(x, w_ih0, w_ih1, x16, w0_16, w1_16);

  // grid = (M/256)*(N/256) = 256*8 = 2048 blocks, 512 threads
  gemm8<NI, f16><<<2048, 512, 0, stream>>>(x16, w0_16, b0, P);
  scan_k<f16, f16><<<BH / 256, 256, 0, stream>>>(P, P, w_hh0);
  if (p2_f16) {
    gemm8<NH, f16><<<2048, 512, 0, stream>>>(P, w1_16, b1, P2);
    scan_k<f16, float><<<BH / 256, 256, 0, stream>>>(P2, out, w_hh1);
  } else {
    gemm8<NH, float><<<2048, 512, 0, stream>>>(P, w1_16, b1, out);
    scan_k<float, float><<<BH / 256, 256, 0, stream>>>(out, out, w_hh1);
  }
}

// Round 9
// 946.412 us; speedup vs baseline: 1.2103x; 1.2103x over previous
//
#include <hip/hip_runtime.h>

// IndRNN: two layers of (GEMM pre-projection + elementwise scan).
//   T=1024, B=64, I=512, H=2048.
// R9: exact revert to R6 (best measured: 947us). R4/R5/R7/R8 all perturbed
// the gemm8 phase interior and all regressed; R6 is the validated optimum:
//   - 16x16x32 f16 MFMA, 256^2 tile, 8 waves (128x64 each), BK=64
//   - quadrant phases, ds 12/4/8/0, stage A1(t+1)/B0(t+1)/A0(t+2)/B1(t+2)
//     placed AFTER each phase's ds_read cluster
//   - raw s_barrier + counted vmcnt(4) at phase 3 only (queue proof in R6)
//   - st-16x32-style XOR swizzle; staging via linear gload_lds dest +
//     inverse-swizzled global source
// Structural plateau analysis: per K-tile per CU, LDS fragment reads ~192KB
// (~2260cy @ 85B/cy) vs MFMA ~2480cy -> phase-serialized ceiling ~52% util;
// measured 48.5%. Scans/cvt at HBM roofline.

#define T_SEQ 1024
#define NB 64
#define NI 512
#define NH 2048
#define BH (NB * NH)
#define M_ROWS (T_SEQ * NB)

typedef _Float16 f16;
typedef __attribute__((ext_vector_type(8))) _Float16 f16x8;
typedef __attribute__((ext_vector_type(4))) _Float16 f16x4;
typedef __attribute__((ext_vector_type(4))) float f32x4;

__device__ __forceinline__ void gload_lds16(const f16* g, const f16* lds) {
  __builtin_amdgcn_global_load_lds(
      (const __attribute__((address_space(1))) unsigned int*)g,
      (__attribute__((address_space(3))) unsigned int*)lds, 16, 0, 0);
}
__device__ __forceinline__ void barrier_raw() {
  __builtin_amdgcn_sched_barrier(0);
  __builtin_amdgcn_s_barrier();
  __builtin_amdgcn_sched_barrier(0);
}
// rule 18: inline-asm lgkmcnt(0) needs a following sched_barrier(0)
#define LGKM0()                                        \
  do {                                                 \
    asm volatile("s_waitcnt lgkmcnt(0)" ::: "memory"); \
    __builtin_amdgcn_sched_barrier(0);                 \
  } while (0)
#define VMCNT4() asm volatile("s_waitcnt vmcnt(4)" ::: "memory")

// ---------------- fp32 -> fp16 conversion, all 3 inputs in one launch -------
__global__ __launch_bounds__(256)
void cvt_all(const float* __restrict__ x, const float* __restrict__ w0,
             const float* __restrict__ w1, f16* __restrict__ x16,
             f16* __restrict__ w0_16, f16* __restrict__ w1_16) {
  constexpr int N0 = 33554432 / 4, N1 = 1048576 / 4, N2 = 4194304 / 4;
  int i = blockIdx.x * 256 + threadIdx.x;
  const int stride = gridDim.x * 256;
  for (; i < N0 + N1 + N2; i += stride) {
    const float* src; f16* dst; int j;
    if (i < N0)            { src = x;  dst = x16;   j = i; }
    else if (i < N0 + N1)  { src = w0; dst = w0_16; j = i - N0; }
    else                   { src = w1; dst = w1_16; j = i - N0 - N1; }
    f32x4 v = ((const f32x4*)src)[j];
    f16x4 h;
    h[0] = (f16)v[0]; h[1] = (f16)v[1]; h[2] = (f16)v[2]; h[3] = (f16)v[3];
    ((f16x4*)dst)[j] = h;
  }
}

// ------- GEMM: C[M,2048] = A[M,K] * Bt[2048,K]^T + bias, 8-phase 256^2 -------
// Wave (wr,wc): wr=wid>>2 (2 M-groups), wc=wid&3 (4 N-groups).
// m-tile mt(0..7) -> C rows (2*mt+wr)*16; A-half = mt>>2 (interleave-by-16).
// n-tile nt(0..3) -> C cols (4*nt+wc)*16; B-half = nt>>1.
// Phases per K-tile: (m0,n0)(m0,n1)(m1,n1)(m1,n0); stages: A1(t+1), B0(t+1),
// A0(t+2), B1(t+2); vmcnt(4) at phase 3 only. Queue proof: end of tile t,
// outstanding = [A0(t+1),B1(t+1)] carried + this tile's 4 stages = 12 instr;
// drain to 4 completes all of t+1, leaves [A0(t+2),B1(t+2)].
template <int K, typename OutT>
__global__ __launch_bounds__(512, 2)
void gemm8(const f16* __restrict__ A, const f16* __restrict__ Bt,
           const float* __restrict__ bias, OutT* __restrict__ C) {
  constexpr int NT = K / 64;
  __shared__ f16 sA[2][2][128 * 64];   // [buf][half][row 128][k 64]
  __shared__ f16 sB[2][2][128 * 64];

  const int tid = threadIdx.x, wid = tid >> 6, lane = tid & 63;
  int id = (int)blockIdx.x;
  id = (id & 7) * 256 + (id >> 3);          // XCD swizzle (2048 % 8 == 0)
  const int bn = id & 7, bm = id >> 3;
  const long m0 = (long)bm * 256, n0 = (long)bn * 256;

  const int wr = wid >> 2, wc = wid & 3;
  const int lrow = lane & 15, lk = (lane >> 4) * 8;

  // ds_read byte offsets: L = (tilebase) + ks*64 + T; phys = L ^ ((row&7)<<4).
  const int xorv = (lrow & 7) << 4;
  const int TxA = (((wr * 16 + lrow) * 128) + lk * 2) ^ xorv;
  const int TxB = (((wc * 16 + lrow) * 128) + lk * 2) ^ xorv;

  auto ldA = [&](int buf, int mt, int ks) -> f16x8 {
    const char* p = (const char*)&sA[buf][mt >> 2][0];
    return *(const f16x8*)(p + (mt & 3) * 4096 + (TxA ^ (ks << 6)));
  };
  auto ldB = [&](int buf, int nt, int ks) -> f16x8 {
    const char* p = (const char*)&sB[buf][nt >> 1][0];
    return *(const f16x8*)(p + (nt & 1) * 8192 + (TxB ^ (ks << 6)));
  };

  // staging: LDS dest linear (base + lane*16 by HW); source pre-swizzled.
  const int srow = wid * 8 + (lane >> 3);
  const int scol = ((lane & 7) ^ ((lane >> 3) & 7)) * 8;
  const int ldst = wid * 512;   // f16 elements; +4096 for inst 1

  auto stageA = [&](int buf, int h, int kt) {
    if (kt >= NT) kt = NT - 1;   // tail clamp: lands in a dead buffer
    const f16* g = A + (m0 + h * 128 + srow) * (long)K + kt * 64 + scol;
    gload_lds16(g,                &sA[buf][h][ldst]);
    gload_lds16(g + 64 * (long)K, &sA[buf][h][ldst + 4096]);
  };
  auto stageB = [&](int buf, int h, int kt) {
    if (kt >= NT) kt = NT - 1;
    const f16* g = Bt + (n0 + h * 128 + srow) * (long)K + kt * 64 + scol;
    gload_lds16(g,                &sB[buf][h][ldst]);
    gload_lds16(g + 64 * (long)K, &sB[buf][h][ldst + 4096]);
  };

  f32x4 acc[8][4] = {};
  f16x8 aR[4][2], bR[4][2];

#define MFMA16(MBASE, NBASE)                                                   \
  __builtin_amdgcn_s_setprio(1);                                               \
  _Pragma("unroll") for (int mi = 0; mi < 4; ++mi)                             \
      _Pragma("unroll") for (int ni = 0; ni < 2; ++ni)                         \
          _Pragma("unroll") for (int ks = 0; ks < 2; ++ks)                     \
              acc[MBASE + mi][NBASE + ni] =                                    \
                  __builtin_amdgcn_mfma_f32_16x16x32_f16(                      \
                      aR[mi][ks], bR[NBASE + ni][ks],                          \
                      acc[MBASE + mi][NBASE + ni], 0, 0, 0);                   \
  __builtin_amdgcn_s_setprio(0);

  // prologue — queue order must match steady state:
  stageA(0, 0, 0);
  stageB(0, 1, 0);
  stageA(0, 1, 0);
  stageB(0, 0, 0);
  stageA(1, 0, 1);
  stageB(1, 1, 1);
  VMCNT4();
  barrier_raw();

  for (int t = 0; t < NT; ++t) {
    const int cur = t & 1, nxt = cur ^ 1;
    // ---- phase 0: (m0,n0); ds: A-half0 + B-half0; stage A1(t+1) ----
#pragma unroll
    for (int i = 0; i < 4; ++i) { aR[i][0] = ldA(cur, i, 0); aR[i][1] = ldA(cur, i, 1); }
#pragma unroll
    for (int i = 0; i < 2; ++i) { bR[i][0] = ldB(cur, i, 0); bR[i][1] = ldB(cur, i, 1); }
    stageA(nxt, 1, t + 1);
    barrier_raw();
    LGKM0();
    MFMA16(0, 0);
    barrier_raw();
    // ---- phase 1: (m0,n1); ds: B-half1; stage B0(t+1) ----
#pragma unroll
    for (int i = 0; i < 2; ++i) { bR[2 + i][0] = ldB(cur, 2 + i, 0); bR[2 + i][1] = ldB(cur, 2 + i, 1); }
    stageB(nxt, 0, t + 1);
    barrier_raw();
    LGKM0();
    MFMA16(0, 2);
    barrier_raw();
    // ---- phase 2: (m1,n1); ds: A-half1; stage A0(t+2) ----
#pragma unroll
    for (int i = 0; i < 4; ++i) { aR[i][0] = ldA(cur, 4 + i, 0); aR[i][1] = ldA(cur, 4 + i, 1); }
    stageA(cur, 0, t + 2);
    barrier_raw();
    LGKM0();
    MFMA16(4, 2);
    barrier_raw();
    // ---- phase 3: (m1,n0); no ds; stage B1(t+2); counted vmcnt ----
    stageB(cur, 1, t + 2);
    barrier_raw();
    MFMA16(4, 0);
    VMCNT4();
    barrier_raw();
  }

  // ---- epilogue: D frag col=lane&15, row=(lane>>4)*4+j ----
  float bv[4];
#pragma unroll
  for (int nt = 0; nt < 4; ++nt) bv[nt] = bias[n0 + (4 * nt + wc) * 16 + lrow];
#pragma unroll
  for (int mt = 0; mt < 8; ++mt) {
    const long rbase = m0 + (2 * mt + wr) * 16 + ((lane >> 4) << 2);
#pragma unroll
    for (int j = 0; j < 4; ++j) {
      OutT* cp = C + (rbase + j) * (long)NH + n0 + wc * 16 + lrow;
#pragma unroll
      for (int nt = 0; nt < 4; ++nt)
        cp[nt * 64] = (OutT)(acc[mt][nt][j] + bv[nt]);
    }
  }
#undef MFMA16
}

// ------------- scan: h[t] = relu(pre[t] + w*h[t-1]); out[t] = h -------------
// One thread per (b,h) channel; fp32 state in regs; 16-deep software prefetch.
// No __restrict__: in==out for the in-place layer-0 use.
template <typename InT, typename OutT>
__global__ __launch_bounds__(256)
void scan_k(const InT* in, OutT* out, const float* __restrict__ w_hh) {
  const int c = blockIdx.x * 256 + threadIdx.x;   // 0..BH-1
  const float w = w_hh[c & (NH - 1)];
  const InT* pi = in + c;
  OutT* po = out + c;
  float h = 0.f, v[16], n[16];
#pragma unroll
  for (int j = 0; j < 16; ++j) v[j] = (float)pi[(long)j * BH];
  for (int t = 0; t < T_SEQ; t += 16) {
    if (t + 16 < T_SEQ) {
#pragma unroll
      for (int j = 0; j < 16; ++j) n[j] = (float)pi[(long)(t + 16 + j) * BH];
    } else {
#pragma unroll
      for (int j = 0; j < 16; ++j) n[j] = 0.f;
    }
#pragma unroll
    for (int j = 0; j < 16; ++j) {
      h = fmaxf(fmaf(w, h, v[j]), 0.f);
      po[(long)(t + j) * BH] = (OutT)h;
      v[j] = n[j];
    }
  }
}

extern "C" void kernel_launch(void* const* d_in, const int* in_sizes, int n_in,
                              void* d_out, int out_size, void* d_ws, size_t ws_size,
                              hipStream_t stream) {
  const float* x     = (const float*)d_in[0];   // [1024,64,512]
  const float* w_ih0 = (const float*)d_in[1];   // [2048,512]
  const float* w_hh0 = (const float*)d_in[2];   // [2048]
  const float* b0    = (const float*)d_in[3];   // [2048]
  const float* w_ih1 = (const float*)d_in[4];   // [2048,2048]
  const float* w_hh1 = (const float*)d_in[5];   // [2048]
  const float* b1    = (const float*)d_in[6];   // [2048]
  float* out = (float*)d_out;                   // [1024,64,2048]

  char* ws = (char*)d_ws;
  f16* x16   = (f16*)(ws);                 // 64 MiB
  f16* w0_16 = (f16*)(ws + 67108864);      //  2 MiB
  f16* w1_16 = (f16*)(ws + 69206016);      //  8 MiB
  f16* P     = (f16*)(ws + 77594624);      // 256 MiB (pre0 -> h0, in-place)
  f16* P2    = (f16*)(ws + 346030080);     // 256 MiB (pre1 fp16), if ws allows
  const bool p2_f16 = ws_size >= (size_t)346030080 + 268435456;

  cvt_all<<<2048, 256, 0, stream>>>(x, w_ih0, w_ih1, x16, w0_16, w1_16);

  // grid = (M/256)*(N/256) = 256*8 = 2048 blocks, 512 threads
  gemm8<NI, f16><<<2048, 512, 0, stream>>>(x16, w0_16, b0, P);
  scan_k<f16, f16><<<BH / 256, 256, 0, stream>>>(P, P, w_hh0);
  if (p2_f16) {
    gemm8<NH, f16><<<2048, 512, 0, stream>>>(P, w1_16, b1, P2);
    scan_k<f16, float><<<BH / 256, 256, 0, stream>>>(P2, out, w_hh1);
  } else {
    gemm8<NH, float><<<2048, 512, 0, stream>>>(P, w1_16, b1, out);
    scan_k<float, float><<<BH / 256, 256, 0, stream>>>(out, out, w_hh1);
  }
}